// Round 2
// baseline (93.799 us; speedup 1.0000x reference)
//
#include <hip/hip_runtime.h>
#include <math.h>

#define CC    144
#define WW    9225
#define KWW   10
#define FF    64
#define H1N   128
#define CONVN (WW - KWW + 1)   // 9216
#define CFN   (CC * FF)        // 9216
#define CATN  (CFN + CONVN)    // 18432

// ---------------------------------------------------------------------------
// Stage 1 fused: blocks [0, CFN) compute fc_out (one (c,f) row-dot per block),
// blocks [CFN, CFN+36) compute the 9216 conv outputs (256 positions/block).
// Writes concat[CATN] into workspace.
// ---------------------------------------------------------------------------
__global__ __launch_bounds__(256) void k_front(
    const float* __restrict__ x,     // [C, W]
    const float* __restrict__ Wfc,   // [C, F, W]
    const float* __restrict__ bfc,   // [C, F]
    const float* __restrict__ Kc,    // [C, KW]
    const float* __restrict__ bconv, // [1]
    float* __restrict__ concat)      // [CATN]
{
    __shared__ float sm[CC * KWW];   // 1440 floats; also reused for reduce
    const int b   = blockIdx.x;
    const int tid = threadIdx.x;

    if (b < CFN) {
        // ------------------ fc: out[b] = dot(Wfc_row, x_row) + bfc[b]
        const int c = b >> 6;                 // b / F
        const size_t base = (size_t)b * WW;   // row start (floats)
        const float* __restrict__ xr = x + (size_t)c * WW;
        const float* __restrict__ wr = Wfc + base;

        // alignment prologue to reach a 16B boundary (W=9225 is odd)
        const int pro = (int)((4u - ((unsigned)(base & 3u))) & 3u);
        float acc = 0.f;
        if (tid < pro) acc += wr[tid] * xr[tid];

        const int rem  = WW - pro;
        const int nv   = rem >> 2;   // number of float4s
        const int tail = rem & 3;
        const float4* __restrict__ wv = (const float4*)(wr + pro);

        for (int i = tid; i < nv; i += 256) {
            const float4 wq = wv[i];
            const int w0 = pro + (i << 2);
            acc += wq.x * xr[w0]     + wq.y * xr[w0 + 1]
                 + wq.z * xr[w0 + 2] + wq.w * xr[w0 + 3];
        }
        if (tid < tail) {
            const int w0 = pro + (nv << 2) + tid;
            acc += wr[w0] * xr[w0];
        }

        // wave reduce (64 lanes) then cross-wave via LDS
        #pragma unroll
        for (int off = 32; off > 0; off >>= 1)
            acc += __shfl_xor(acc, off, 64);
        const int lane = tid & 63, wid = tid >> 6;
        if (lane == 0) sm[wid] = acc;
        __syncthreads();
        if (tid == 0)
            concat[b] = sm[0] + sm[1] + sm[2] + sm[3] + bfc[b];
    } else {
        // ------------------ conv: position p = (b-CFN)*256 + tid
        for (int i = tid; i < CC * KWW; i += 256) sm[i] = Kc[i];
        __syncthreads();

        const int p = (b - CFN) * 256 + tid;          // 36*256 == 9216 exactly
        float acc = bconv[0];
        for (int c = 0; c < CC; ++c) {
            const float* __restrict__ xr = x + (size_t)c * WW + p;
            const float* __restrict__ kr = sm + c * KWW;
            #pragma unroll
            for (int k = 0; k < KWW; ++k)
                acc = fmaf(xr[k], kr[k], acc);
        }
        concat[CFN + p] = acc;
    }
}

// ---------------------------------------------------------------------------
// Stage 2: second[h] = relu(dot(W1[h,:], concat) + b1[h]) ; 128 blocks
// ---------------------------------------------------------------------------
__global__ __launch_bounds__(256) void k_layer1(
    const float* __restrict__ W1,     // [H1, CAT]
    const float* __restrict__ b1,     // [H1]
    const float* __restrict__ concat, // [CAT]
    float* __restrict__ second)       // [H1]
{
    __shared__ float sm[4];
    const int h = blockIdx.x, tid = threadIdx.x;
    const float4* __restrict__ wr = (const float4*)(W1 + (size_t)h * CATN);
    const float4* __restrict__ cv = (const float4*)concat;

    float acc = 0.f;
    #pragma unroll 2
    for (int i = tid; i < CATN / 4; i += 256) {   // 4608/256 = 18 iters
        const float4 a = wr[i], q = cv[i];
        acc += a.x * q.x + a.y * q.y + a.z * q.z + a.w * q.w;
    }
    #pragma unroll
    for (int off = 32; off > 0; off >>= 1)
        acc += __shfl_xor(acc, off, 64);
    if ((tid & 63) == 0) sm[tid >> 6] = acc;
    __syncthreads();
    if (tid == 0)
        second[h] = fmaxf(sm[0] + sm[1] + sm[2] + sm[3] + b1[h], 0.f);
}

// ---------------------------------------------------------------------------
// Stage 3: out = sigmoid(relu(dot(W2, second) + b2)) ; 1 block / 128 threads
// ---------------------------------------------------------------------------
__global__ __launch_bounds__(128) void k_final(
    const float* __restrict__ second, // [H1]
    const float* __restrict__ W2,     // [1, H1]
    const float* __restrict__ b2,     // [1]
    float* __restrict__ out)          // [1]
{
    __shared__ float sm[2];
    const int tid = threadIdx.x;
    float v = second[tid] * W2[tid];
    #pragma unroll
    for (int off = 32; off > 0; off >>= 1)
        v += __shfl_xor(v, off, 64);
    if ((tid & 63) == 0) sm[tid >> 6] = v;
    __syncthreads();
    if (tid == 0) {
        float z = sm[0] + sm[1] + b2[0];
        z = fmaxf(z, 0.f);
        out[0] = 1.f / (1.f + expf(-z));
    }
}

extern "C" void kernel_launch(void* const* d_in, const int* in_sizes, int n_in,
                              void* d_out, int out_size, void* d_ws, size_t ws_size,
                              hipStream_t stream) {
    const float* x     = (const float*)d_in[0];
    const float* Wfc   = (const float*)d_in[1];
    const float* bfc   = (const float*)d_in[2];
    const float* Kc    = (const float*)d_in[3];
    const float* bconv = (const float*)d_in[4];
    const float* W1    = (const float*)d_in[5];
    const float* b1    = (const float*)d_in[6];
    const float* W2    = (const float*)d_in[7];
    const float* b2    = (const float*)d_in[8];
    float* out = (float*)d_out;

    float* concat = (float*)d_ws;          // [CATN]
    float* second = concat + CATN;         // [H1]

    k_front <<<CFN + (CONVN / 256), 256, 0, stream>>>(x, Wfc, bfc, Kc, bconv, concat);
    k_layer1<<<H1N,                 256, 0, stream>>>(W1, b1, concat, second);
    k_final <<<1,                   128, 0, stream>>>(second, W2, b2, out);
}